// Round 11
// baseline (283.227 us; speedup 1.0000x reference)
//
#include <hip/hip_runtime.h>
#include <hip/hip_fp16.h>

// ---------------------------------------------------------------------------
// GraphEncoderNetwork: GCNConv(mlp1 -> norm scatter -> mlp2) + pooled mlp_dag
// + global mlp. All fp32. N=200000, E=6400000, G=1000, IN=16, D=16.
//
// Round 11: k_agg accumulate was imbalanced (2 thr/node, degree tail) and
// barrier-heavy. Now: balanced 16-edge slices per thread over the sorted
// array, register partials flushed to LDS acc at node boundaries; wave-level
// shfl scan (5 barriers/chunk). k_scat2 -> 512 thr (32 waves/CU) + 2-level
// wave scan. k_pool+k_dag fused (k_poold).
// ---------------------------------------------------------------------------

#define BSH 8               // bucket shift
#define BSZ 256             // nodes per bucket
#define NBMAX 1024          // max buckets (N <= 2^18)
#define TSZ 4096            // edges per partition tile
#define ATSZ 8192           // edges per k_agg sort chunk
#define CH 16               // chunks per column scan

__device__ __forceinline__ int lowerb(const int* __restrict__ b, int n, int v) {
  int lo = 0, hi = n;
  while (lo < hi) { int m = (lo + hi) >> 1; if (b[m] < v) lo = m + 1; else hi = m; }
  return lo;
}

__device__ __forceinline__ void addmsg(float* acc, uint4 g) {
  const __half2* h2 = reinterpret_cast<const __half2*>(&g);
  #pragma unroll
  for (int q = 0; q < 4; q++) {
    float2 f = __half22float2(h2[q]);
    acc[2 * q] += f.x;
    acc[2 * q + 1] += f.y;
  }
}

// ---------------- bucketing machinery (atomic-free partition) --------------

// per-tile histogram of row and col keys -> Hr[t][b], Hc[t][b]
__global__ void __launch_bounds__(256)
k_hist(const int* __restrict__ row, const int* __restrict__ col, int E,
       int NBP, unsigned* __restrict__ Hr, unsigned* __restrict__ Hc) {
  __shared__ unsigned hr[NBMAX], hc[NBMAX];
  int t = threadIdx.x;
  int base = blockIdx.x * TSZ;
  int cnt = min(TSZ, E - base);
  for (int i = t; i < NBP; i += 256) { hr[i] = 0; hc[i] = 0; }
  __syncthreads();
  #pragma unroll
  for (int u = 0; u < 4; u++) {
    int idx = base + 4 * (t + 256 * u);
    unsigned rv[4], cv[4];
    if (idx + 3 < E) {
      uint4 r4 = *reinterpret_cast<const uint4*>(row + idx);
      uint4 c4 = *reinterpret_cast<const uint4*>(col + idx);
      rv[0] = r4.x; rv[1] = r4.y; rv[2] = r4.z; rv[3] = r4.w;
      cv[0] = c4.x; cv[1] = c4.y; cv[2] = c4.z; cv[3] = c4.w;
    } else {
      #pragma unroll
      for (int j = 0; j < 4; j++) {
        bool v = (idx + j) < E;
        rv[j] = v ? (unsigned)row[idx + j] : 0u;
        cv[j] = v ? (unsigned)col[idx + j] : 0u;
      }
    }
    int l0 = 4 * (t + 256 * u);
    #pragma unroll
    for (int j = 0; j < 4; j++) {
      if (l0 + j < cnt) {
        atomicAdd(&hr[rv[j] >> BSH], 1u);
        atomicAdd(&hc[cv[j] >> BSH], 1u);
      }
    }
  }
  __syncthreads();
  size_t rb = (size_t)blockIdx.x * NBP;
  for (int i = t; i < NBP; i += 256) {
    Hr[rb + i] = hr[i];
    Hc[rb + i] = hc[i];
  }
}

// chunk sums per bucket column (row half then col half of the grid)
__global__ void __launch_bounds__(256)
k_colsum2(const unsigned* __restrict__ Hr, unsigned* __restrict__ Sr,
          const unsigned* __restrict__ Hc, unsigned* __restrict__ Sc,
          int NT, int NBP, int CSZ, int gcol) {
  int blk = blockIdx.x;
  const unsigned* H = Hr; unsigned* S = Sr;
  if (blk >= gcol) { blk -= gcol; H = Hc; S = Sc; }
  int i = blk * 256 + threadIdx.x;
  if (i >= CH * NBP) return;
  int ch = i / NBP, b = i - ch * NBP;
  int t0 = ch * CSZ, t1 = min(NT, t0 + CSZ);
  unsigned s = 0;
  for (int t = t0; t < t1; t++) s += H[(size_t)t * NBP + b];
  S[i] = s;
}

// in-place exclusive prefix over tiles per bucket; emit per-bucket totals
__global__ void __launch_bounds__(256)
k_colapply2(unsigned* __restrict__ Hr, const unsigned* __restrict__ Sr,
            unsigned* __restrict__ tot_r,
            unsigned* __restrict__ Hc, const unsigned* __restrict__ Sc,
            unsigned* __restrict__ tot_c,
            int NT, int NBP, int nb, int CSZ, int gcol) {
  int blk = blockIdx.x;
  unsigned* H = Hr; const unsigned* S = Sr; unsigned* tot = tot_r;
  if (blk >= gcol) { blk -= gcol; H = Hc; S = Sc; tot = tot_c; }
  int i = blk * 256 + threadIdx.x;
  if (i >= CH * NBP) return;
  int ch = i / NBP, b = i - ch * NBP;
  unsigned run = 0;
  for (int c = 0; c < ch; c++) run += S[c * NBP + b];
  int t0 = ch * CSZ, t1 = min(NT, t0 + CSZ);
  for (int t = t0; t < t1; t++) {
    unsigned v = H[(size_t)t * NBP + b];
    H[(size_t)t * NBP + b] = run;
    run += v;
  }
  if (ch == CH - 1 && b < nb) tot[b] = run;
}

// fused scan over dense totals: block 0 row (pad x4), block 1 col
__global__ void __launch_bounds__(1024)
k_scan2(const unsigned* __restrict__ tot_r, unsigned* __restrict__ offs_r,
        const unsigned* __restrict__ tot_c, unsigned* __restrict__ offs_c,
        int nb) {
  const unsigned* tot = blockIdx.x ? tot_c : tot_r;
  unsigned* offs = blockIdx.x ? offs_c : offs_r;
  unsigned pm1 = blockIdx.x ? 0u : 3u;
  __shared__ unsigned s[1024];
  int t = threadIdx.x;
  unsigned e0 = (2 * t < nb) ? ((tot[2 * t] + pm1) & ~pm1) : 0u;
  unsigned e1 = (2 * t + 1 < nb) ? ((tot[2 * t + 1] + pm1) & ~pm1) : 0u;
  unsigned sum = e0 + e1;
  s[t] = sum;
  __syncthreads();
  for (int d = 1; d < 1024; d <<= 1) {
    unsigned v = (t >= d) ? s[t - d] : 0u;
    __syncthreads();
    s[t] += v;
    __syncthreads();
  }
  unsigned ex = s[t] - sum;
  if (2 * t < nb)     offs[2 * t] = ex;
  if (2 * t + 1 < nb) offs[2 * t + 1] = ex + e0;
}

// tile-local LDS reorder scatter, fused hist+rank, deterministic bases,
// 512 threads, 2-level wave scan
__global__ void __launch_bounds__(512)
k_scat2(const int* __restrict__ row, const int* __restrict__ col, int E, int nb,
        int NBP,
        const unsigned* __restrict__ Hr, const unsigned* __restrict__ Hc,
        const unsigned* __restrict__ offs_r, const unsigned* __restrict__ offs_c,
        unsigned* __restrict__ ebuf, unsigned short* __restrict__ ebuf2) {
  __shared__ unsigned buf[TSZ];            // 16KB reordered payloads
  __shared__ unsigned short bkt[TSZ];      // 8KB bucket id per slot
  __shared__ unsigned h[NBMAX], diff[NBMAX];  // 8KB
  __shared__ unsigned wtot[4];
  int t = threadIdx.x;
  int base = blockIdx.x * TSZ;
  int cnt = min(TSZ, E - base);
  size_t hrow = (size_t)blockIdx.x * NBP;

  unsigned rv[8], cv[8];
  #pragma unroll
  for (int u = 0; u < 2; u++) {
    int idx = base + 4 * (t + 512 * u);
    if (idx + 3 < E) {
      uint4 r4 = *reinterpret_cast<const uint4*>(row + idx);
      uint4 c4 = *reinterpret_cast<const uint4*>(col + idx);
      rv[4*u] = r4.x; rv[4*u+1] = r4.y; rv[4*u+2] = r4.z; rv[4*u+3] = r4.w;
      cv[4*u] = c4.x; cv[4*u+1] = c4.y; cv[4*u+2] = c4.z; cv[4*u+3] = c4.w;
    } else {
      #pragma unroll
      for (int j = 0; j < 4; j++) {
        bool v = (idx + j) < E;
        rv[4*u+j] = v ? (unsigned)row[idx + j] : 0u;
        cv[4*u+j] = v ? (unsigned)col[idx + j] : 0u;
      }
    }
  }

  // ================= ROW PASS =================
  for (int i = t; i < NBMAX; i += 512) h[i] = 0;
  __syncthreads();
  unsigned rk[8];
  #pragma unroll
  for (int u = 0; u < 2; u++) {
    int l0 = 4 * (t + 512 * u);
    #pragma unroll
    for (int j = 0; j < 4; j++)
      if (l0 + j < cnt) rk[4*u+j] = atomicAdd(&h[rv[4*u+j] >> BSH], 1u);
  }
  __syncthreads();
  unsigned a0 = 0, a1 = 0, a2 = 0, a3 = 0, p1 = 0, p2 = 0, p3 = 0, isum = 0;
  if (t < 256) {
    a0 = h[4*t]; a1 = h[4*t+1]; a2 = h[4*t+2]; a3 = h[4*t+3];
    p1 = a0 + a1; p2 = p1 + a2; p3 = p2 + a3;
    isum = p3;
    #pragma unroll
    for (int d = 1; d < 64; d <<= 1) {
      unsigned o = __shfl_up(isum, d, 64);
      if ((t & 63) >= d) isum += o;
    }
    if ((t & 63) == 63) wtot[t >> 6] = isum;
  }
  __syncthreads();
  if (t < 256) {
    unsigned woff = 0;
    for (int w = 0; w < (t >> 6); w++) woff += wtot[w];
    unsigned ex = woff + isum - p3;
    unsigned l[4] = {ex, ex + a0, ex + p1, ex + p2};
    #pragma unroll
    for (int k = 0; k < 4; k++) {
      int b = 4 * t + k;
      h[b] = l[k];
      if (b < nb) diff[b] = offs_r[b] + Hr[hrow + b] - l[k];
    }
  }
  __syncthreads();
  #pragma unroll
  for (int u = 0; u < 2; u++) {
    int l0 = 4 * (t + 512 * u);
    #pragma unroll
    for (int j = 0; j < 4; j++) {
      if (l0 + j < cnt) {
        unsigned r = rv[4*u+j], b = r >> BSH;
        unsigned pos = h[b] + rk[4*u+j];
        buf[pos] = ((r & (BSZ - 1u)) << 18) | cv[4*u+j];
        bkt[pos] = (unsigned short)b;
      }
    }
  }
  __syncthreads();
  #pragma unroll
  for (int u = 0; u < 8; u++) {
    int s2 = t + 512 * u;
    if (s2 < cnt) ebuf[(unsigned)s2 + diff[bkt[s2]]] = buf[s2];
  }
  __syncthreads();

  // ================= COL PASS =================
  for (int i = t; i < NBMAX; i += 512) h[i] = 0;
  __syncthreads();
  #pragma unroll
  for (int u = 0; u < 2; u++) {
    int l0 = 4 * (t + 512 * u);
    #pragma unroll
    for (int j = 0; j < 4; j++)
      if (l0 + j < cnt) rk[4*u+j] = atomicAdd(&h[cv[4*u+j] >> BSH], 1u);
  }
  __syncthreads();
  a0 = a1 = a2 = a3 = p1 = p2 = p3 = isum = 0;
  if (t < 256) {
    a0 = h[4*t]; a1 = h[4*t+1]; a2 = h[4*t+2]; a3 = h[4*t+3];
    p1 = a0 + a1; p2 = p1 + a2; p3 = p2 + a3;
    isum = p3;
    #pragma unroll
    for (int d = 1; d < 64; d <<= 1) {
      unsigned o = __shfl_up(isum, d, 64);
      if ((t & 63) >= d) isum += o;
    }
    if ((t & 63) == 63) wtot[t >> 6] = isum;
  }
  __syncthreads();
  if (t < 256) {
    unsigned woff = 0;
    for (int w = 0; w < (t >> 6); w++) woff += wtot[w];
    unsigned ex = woff + isum - p3;
    unsigned l[4] = {ex, ex + a0, ex + p1, ex + p2};
    #pragma unroll
    for (int k = 0; k < 4; k++) {
      int b = 4 * t + k;
      h[b] = l[k];
      if (b < nb) diff[b] = offs_c[b] + Hc[hrow + b] - l[k];
    }
  }
  __syncthreads();
  #pragma unroll
  for (int u = 0; u < 2; u++) {
    int l0 = 4 * (t + 512 * u);
    #pragma unroll
    for (int j = 0; j < 4; j++) {
      if (l0 + j < cnt) {
        unsigned c = cv[4*u+j], b = c >> BSH;
        unsigned pos = h[b] + rk[4*u+j];
        buf[pos] = c & (BSZ - 1u);
        bkt[pos] = (unsigned short)b;
      }
    }
  }
  __syncthreads();
  #pragma unroll
  for (int u = 0; u < 8; u++) {
    int s2 = t + 512 * u;
    if (s2 < cnt) ebuf2[(unsigned)s2 + diff[bkt[s2]]] = (unsigned short)buf[s2];
  }
}

// ---------------- fused degree + mlp1 --------------------------------------

__global__ void __launch_bounds__(256)
k_degm(const unsigned short* __restrict__ eb, const unsigned* __restrict__ offs_c,
       const unsigned* __restrict__ tot_c,
       const float* __restrict__ x,
       const float* __restrict__ w1, const float* __restrict__ b1,
       const float* __restrict__ w2, const float* __restrict__ b2,
       const float* __restrict__ w3, const float* __restrict__ b3,
       unsigned* __restrict__ deg, uint4* __restrict__ hs16, int N) {
  __shared__ unsigned cnt[BSZ];
  __shared__ float sW1[16 * 32], sB1[32], sW2[32 * 16], sB2[16], sW3[16 * 8], sB3[8];
  int b = blockIdx.x, t = threadIdx.x;
  cnt[t] = 0;
  sW1[t] = w1[t]; sW1[t + 256] = w1[t + 256];
  sW2[t] = w2[t]; sW2[t + 256] = w2[t + 256];
  if (t < 128) sW3[t] = w3[t];
  if (t < 32) sB1[t] = b1[t];
  if (t < 16) sB2[t] = b2[t];
  if (t < 8) sB3[t] = b3[t];
  __syncthreads();
  unsigned s = offs_c[b], n = tot_c[b];
  for (unsigned i = t; i < n; i += 256) atomicAdd(&cnt[eb[s + i]], 1u);
  __syncthreads();
  int node = b * BSZ + t;
  if (node >= N) return;
  unsigned d = cnt[t];
  deg[node] = d;

  float xin[16];
  const float4* xp = reinterpret_cast<const float4*>(x + (size_t)node * 16);
  #pragma unroll
  for (int q = 0; q < 4; q++) {
    float4 v = xp[q];
    xin[q * 4 + 0] = v.x; xin[q * 4 + 1] = v.y; xin[q * 4 + 2] = v.z; xin[q * 4 + 3] = v.w;
  }
  float h1[32];
  #pragma unroll
  for (int o = 0; o < 32; o++) {
    float s1 = sB1[o];
    #pragma unroll
    for (int k = 0; k < 16; k++) s1 = fmaf(xin[k], sW1[k * 32 + o], s1);
    h1[o] = fmaxf(s1, 0.f);
  }
  float h2[16];
  #pragma unroll
  for (int o = 0; o < 16; o++) {
    float s1 = sB2[o];
    #pragma unroll
    for (int k = 0; k < 32; k++) s1 = fmaf(h1[k], sW2[k * 16 + o], s1);
    h2[o] = fmaxf(s1, 0.f);
  }
  float dinv = rsqrtf((float)(d + 1u));  // +1 self-loop
  float o0[8];
  #pragma unroll
  for (int o = 0; o < 8; o++) {
    float s1 = sB3[o];
    #pragma unroll
    for (int k = 0; k < 16; k++) s1 = fmaf(h2[k], sW3[k * 8 + o], s1);
    o0[o] = dinv * s1;
  }
  __half2 hh[4];
  #pragma unroll
  for (int q = 0; q < 4; q++) hh[q] = __floats2half2_rn(o0[2 * q], o0[2 * q + 1]);
  hs16[node] = *reinterpret_cast<const uint4*>(hh);
}

// ---------------- aggregation (512 thr, balanced slices) -------------------

__global__ void __launch_bounds__(512)
k_agg(const unsigned* __restrict__ ebuf, const unsigned* __restrict__ offs,
      const unsigned* __restrict__ tot,
      const uint4* __restrict__ hs16, const unsigned* __restrict__ deg,
      const float* __restrict__ w1, const float* __restrict__ b1,
      const float* __restrict__ w2, const float* __restrict__ b2,
      const float* __restrict__ w3, const float* __restrict__ b3,
      float* __restrict__ xn, int N) {
  __shared__ unsigned sorted[ATSZ];        // 32KB
  __shared__ unsigned hist[256];
  __shared__ unsigned cum[257];
  __shared__ unsigned wtot[4];
  __shared__ float acc[8][BSZ];            // 8KB channel-major
  __shared__ float sW1[256], sB1[32], sW2[512], sB2[16], sW3[256], sB3[16];
  int t = threadIdx.x;
  if (t < 256) { sW1[t] = w1[t]; sW3[t] = w3[t]; }
  else { int u = t - 256; sW2[u] = w2[u]; sW2[u + 256] = w2[u + 256]; }
  if (t < 32) sB1[t] = b1[t];
  if (t < 16) { sB2[t] = b2[t]; sB3[t] = b3[t]; }
  for (int i = t; i < 8 * BSZ; i += 512) (&acc[0][0])[i] = 0.f;

  int b = blockIdx.x;
  unsigned s = offs[b], n = tot[b];
  unsigned nr = (n + 3u) & ~3u;            // padded region is allocated

  for (unsigned c0 = 0; c0 < n; c0 += ATSZ) {
    unsigned chn = min(n - c0, (unsigned)ATSZ);
    if (t < 256) hist[t] = 0;
    __syncthreads();

    unsigned rel[16], colv[16], rk[16];
    #pragma unroll
    for (int u = 0; u < 4; u++) {
      unsigned idx = c0 + 4 * (unsigned)(t + 512 * u);
      uint4 pk = make_uint4(0u, 0u, 0u, 0u);
      if (idx < nr) pk = *reinterpret_cast<const uint4*>(ebuf + s + idx);
      #pragma unroll
      for (int j = 0; j < 4; j++) {
        bool real = (idx + j) < n;
        unsigned p = (&pk.x)[j];
        rel[4*u+j]  = real ? (p >> 18) : 256u;     // 256 = sentinel
        colv[4*u+j] = p & 0x3FFFFu;
      }
    }
    #pragma unroll
    for (int u = 0; u < 16; u++)
      if (rel[u] < 256u) rk[u] = atomicAdd(&hist[rel[u]], 1u);
    __syncthreads();
    // wave-0 scan of 256 bins (4 bins/lane, shfl inclusive scan)
    if (t < 64) {
      unsigned v0 = hist[4*t], v1 = hist[4*t+1], v2 = hist[4*t+2], v3 = hist[4*t+3];
      unsigned q1 = v0 + v1, q2 = q1 + v2, q3 = q2 + v3;
      unsigned isum = q3;
      #pragma unroll
      for (int d = 1; d < 64; d <<= 1) {
        unsigned o = __shfl_up(isum, d, 64);
        if (t >= d) isum += o;
      }
      unsigned ex = isum - q3;
      cum[4*t] = ex; cum[4*t+1] = ex + v0; cum[4*t+2] = ex + q1; cum[4*t+3] = ex + q2;
      if (t == 63) cum[256] = isum;
    }
    __syncthreads();
    #pragma unroll
    for (int u = 0; u < 16; u++) {
      if (rel[u] < 256u) sorted[cum[rel[u]] + rk[u]] = colv[u];
    }
    __syncthreads();

    // balanced slice accumulation: 16 edges/thread, flush at node boundaries
    unsigned lo = (unsigned)t * 16u;
    unsigned hi = min(chn, lo + 16u);
    if (lo < hi) {
      int a = 1, bnd = 256;
      while (a < bnd) { int m = (a + bnd) >> 1; if (cum[m] <= lo) a = m + 1; else bnd = m; }
      int nd = a - 1;
      float part[8];
      #pragma unroll
      for (int c = 0; c < 8; c++) part[c] = 0.f;
      bool dirty = false;
      unsigned i = lo;
      while (i < hi) {
        while (i >= cum[nd + 1]) {
          if (dirty) {
            #pragma unroll
            for (int c = 0; c < 8; c++) atomicAdd(&acc[c][nd], part[c]);
            #pragma unroll
            for (int c = 0; c < 8; c++) part[c] = 0.f;
            dirty = false;
          }
          nd++;
        }
        unsigned lim = min(hi, cum[nd + 1]);
        for (; i + 4 <= lim; i += 4) {
          unsigned q0 = sorted[i], q1 = sorted[i+1], q2 = sorted[i+2], q3 = sorted[i+3];
          uint4 g0 = hs16[q0];
          uint4 g1 = hs16[q1];
          uint4 g2 = hs16[q2];
          uint4 g3 = hs16[q3];
          addmsg(part, g0); addmsg(part, g1); addmsg(part, g2); addmsg(part, g3);
          dirty = true;
        }
        for (; i < lim; i++) { uint4 g = hs16[sorted[i]]; addmsg(part, g); dirty = true; }
      }
      if (dirty) {
        #pragma unroll
        for (int c = 0; c < 8; c++) atomicAdd(&acc[c][nd], part[c]);
      }
    }
    __syncthreads();
  }

  if (t >= 256) return;
  int node = b * BSZ + t;
  if (node >= N) return;
  float dinv = rsqrtf((float)(deg[node] + 1u));
  uint4 selfp = hs16[node];
  const __half2* sh = reinterpret_cast<const __half2*>(&selfp);
  float a[8];
  #pragma unroll
  for (int q = 0; q < 4; q++) {
    float2 f = __half22float2(sh[q]);
    a[2 * q]     = dinv * (acc[2 * q][t] + f.x);
    a[2 * q + 1] = dinv * (acc[2 * q + 1][t] + f.y);
  }

  float h1[32];
  #pragma unroll
  for (int o = 0; o < 32; o++) {
    float v = sB1[o];
    #pragma unroll
    for (int k = 0; k < 8; k++) v = fmaf(a[k], sW1[k * 32 + o], v);
    h1[o] = fmaxf(v, 0.f);
  }
  float h2v[16];
  #pragma unroll
  for (int o = 0; o < 16; o++) {
    float v = sB2[o];
    #pragma unroll
    for (int k = 0; k < 32; k++) v = fmaf(h1[k], sW2[k * 16 + o], v);
    h2v[o] = fmaxf(v, 0.f);
  }
  float o0[16];
  #pragma unroll
  for (int o = 0; o < 16; o++) {
    float v = sB3[o];
    #pragma unroll
    for (int k = 0; k < 16; k++) v = fmaf(h2v[k], sW3[k * 16 + o], v);
    o0[o] = v;
  }
  float4* op = reinterpret_cast<float4*>(xn + (size_t)node * 16);
  #pragma unroll
  for (int q = 0; q < 4; q++)
    op[q] = make_float4(o0[q * 4], o0[q * 4 + 1], o0[q * 4 + 2], o0[q * 4 + 3]);
}

// ---------------- fused pool + mlp_dag -------------------------------------

__global__ void __launch_bounds__(256)
k_poold(const float* __restrict__ x, const float* __restrict__ xn,
        const int* __restrict__ batch,
        const float* __restrict__ w1, const float* __restrict__ b1,
        const float* __restrict__ w2, const float* __restrict__ b2,
        const float* __restrict__ w3, const float* __restrict__ b3,
        float* __restrict__ y, int N) {
  __shared__ float red[8][33];
  __shared__ float pv[32], h1s[32];
  __shared__ float sW1[1024], sW2[512], sW3[256], sB1[32], sB2[16], sB3[16];
  int t = threadIdx.x;
  for (int i = t; i < 1024; i += 256) sW1[i] = w1[i];
  for (int i = t; i < 512; i += 256) sW2[i] = w2[i];
  if (t < 256) sW3[t] = w3[t];
  if (t < 32) sB1[t] = b1[t];
  if (t < 16) { sB2[t] = b2[t]; sB3[t] = b3[t]; }

  int g = blockIdx.x;
  int lo = lowerb(batch, N, g);
  int hi = lowerb(batch, N, g + 1);
  int c = t & 31;
  int j = t >> 5;
  float s = 0.f;
  for (int n = lo + j; n < hi; n += 8) {
    s += (c < 16) ? x[(size_t)n * 16 + c] : xn[(size_t)n * 16 + (c - 16)];
  }
  red[j][c] = s;
  __syncthreads();
  if (t < 32) {
    float v = 0.f;
    #pragma unroll
    for (int q = 0; q < 8; q++) v += red[q][t];
    pv[t] = v;
  }
  __syncthreads();
  if (t < 32) {
    float s1 = sB1[t];
    #pragma unroll
    for (int k = 0; k < 32; k++) s1 = fmaf(pv[k], sW1[k * 32 + t], s1);
    h1s[t] = fmaxf(s1, 0.f);
  }
  __syncthreads();
  if (t < 16) {
    float s2 = sB2[t];
    #pragma unroll
    for (int k = 0; k < 32; k++) s2 = fmaf(h1s[k], sW2[k * 16 + t], s2);
    float h2 = fmaxf(s2, 0.f);
    red[0][t] = h2;   // reuse red row as h2 store
  }
  __syncthreads();
  if (t < 16) {
    float s3 = sB3[t];
    #pragma unroll
    for (int k = 0; k < 16; k++) s3 = fmaf(red[0][k], sW3[k * 16 + t], s3);
    y[(size_t)g * 16 + t] = s3;
  }
}

__global__ void __launch_bounds__(256)
k_z(const float* __restrict__ y,
    const float* __restrict__ w1, const float* __restrict__ b1,
    const float* __restrict__ w2, const float* __restrict__ b2,
    const float* __restrict__ w3, const float* __restrict__ b3,
    float* __restrict__ z, int G) {
  __shared__ float red[16][17];
  __shared__ float sum[16], h1s[32], h2s[16];
  int t = threadIdx.x;
  int c = t & 15, j = t >> 4;
  float s = 0.f;
  for (int g = j; g < G; g += 16) s += y[(size_t)g * 16 + c];
  red[j][c] = s;
  __syncthreads();
  if (t < 16) {
    float v = 0.f;
    #pragma unroll
    for (int q = 0; q < 16; q++) v += red[q][t];
    sum[t] = v;
  }
  __syncthreads();
  if (t < 32) {
    float s1 = b1[t];
    #pragma unroll
    for (int k = 0; k < 16; k++) s1 = fmaf(sum[k], w1[k * 32 + t], s1);
    h1s[t] = fmaxf(s1, 0.f);
  }
  __syncthreads();
  if (t < 16) {
    float s2 = b2[t];
    #pragma unroll
    for (int k = 0; k < 32; k++) s2 = fmaf(h1s[k], w2[k * 16 + t], s2);
    h2s[t] = fmaxf(s2, 0.f);
  }
  __syncthreads();
  if (t < 16) {
    float s3 = b3[t];
    #pragma unroll
    for (int k = 0; k < 16; k++) s3 = fmaf(h2s[k], w3[k * 16 + t], s3);
    z[t] = s3;
  }
}

// ---------------- fallback (known-good atomic path) ------------------------

__global__ void k_deg_atomic(const int* __restrict__ col, unsigned* __restrict__ deg, int E) {
  int e = blockIdx.x * blockDim.x + threadIdx.x;
  if (e < E) atomicAdd(&deg[col[e]], 1u);
}

__global__ void __launch_bounds__(256)
k_mlp1f(const float* __restrict__ x, const unsigned* __restrict__ deg,
        const float* __restrict__ w1, const float* __restrict__ b1,
        const float* __restrict__ w2, const float* __restrict__ b2,
        const float* __restrict__ w3, const float* __restrict__ b3,
        float* __restrict__ hs, int N) {
  __shared__ float sW1[16 * 32], sB1[32], sW2[32 * 16], sB2[16], sW3[16 * 8], sB3[8];
  for (int t = threadIdx.x; t < 512; t += blockDim.x) { sW1[t] = w1[t]; sW2[t] = w2[t]; }
  for (int t = threadIdx.x; t < 128; t += blockDim.x) sW3[t] = w3[t];
  for (int t = threadIdx.x; t < 32; t += blockDim.x) sB1[t] = b1[t];
  for (int t = threadIdx.x; t < 16; t += blockDim.x) sB2[t] = b2[t];
  for (int t = threadIdx.x; t < 8; t += blockDim.x) sB3[t] = b3[t];
  __syncthreads();
  int i = blockIdx.x * blockDim.x + threadIdx.x;
  if (i >= N) return;
  float xin[16];
  const float4* xp = reinterpret_cast<const float4*>(x + (size_t)i * 16);
  #pragma unroll
  for (int q = 0; q < 4; q++) {
    float4 v = xp[q];
    xin[q * 4 + 0] = v.x; xin[q * 4 + 1] = v.y; xin[q * 4 + 2] = v.z; xin[q * 4 + 3] = v.w;
  }
  float h1[32];
  #pragma unroll
  for (int o = 0; o < 32; o++) {
    float s = sB1[o];
    #pragma unroll
    for (int k = 0; k < 16; k++) s = fmaf(xin[k], sW1[k * 32 + o], s);
    h1[o] = fmaxf(s, 0.f);
  }
  float h2[16];
  #pragma unroll
  for (int o = 0; o < 16; o++) {
    float s = sB2[o];
    #pragma unroll
    for (int k = 0; k < 32; k++) s = fmaf(h1[k], sW2[k * 16 + o], s);
    h2[o] = fmaxf(s, 0.f);
  }
  float dinv = rsqrtf((float)(deg[i] + 1u));
  float o0[8];
  #pragma unroll
  for (int o = 0; o < 8; o++) {
    float s = sB3[o];
    #pragma unroll
    for (int k = 0; k < 16; k++) s = fmaf(h2[k], sW3[k * 8 + o], s);
    o0[o] = dinv * s;
  }
  float4* hp = reinterpret_cast<float4*>(hs + (size_t)i * 8);
  hp[0] = make_float4(o0[0], o0[1], o0[2], o0[3]);
  hp[1] = make_float4(o0[4], o0[5], o0[6], o0[7]);
}

__global__ void k_scatter_atomic(const int* __restrict__ row, const int* __restrict__ col,
                                 const float* __restrict__ hs, float* __restrict__ acc, int E) {
  int e = blockIdx.x * blockDim.x + threadIdx.x;
  if (e >= E) return;
  int r = row[e], c = col[e];
  const float4* hp = reinterpret_cast<const float4*>(hs + (size_t)c * 8);
  float4 a = hp[0], b = hp[1];
  float* ap = acc + (size_t)r * 8;
  atomicAdd(ap + 0, a.x); atomicAdd(ap + 1, a.y);
  atomicAdd(ap + 2, a.z); atomicAdd(ap + 3, a.w);
  atomicAdd(ap + 4, b.x); atomicAdd(ap + 5, b.y);
  atomicAdd(ap + 6, b.z); atomicAdd(ap + 7, b.w);
}

__global__ void __launch_bounds__(256)
k_finalize(const float* __restrict__ hs, const float* __restrict__ acc,
           const unsigned* __restrict__ deg,
           const float* __restrict__ w1, const float* __restrict__ b1,
           const float* __restrict__ w2, const float* __restrict__ b2,
           const float* __restrict__ w3, const float* __restrict__ b3,
           float* __restrict__ xn, int N) {
  __shared__ float sW1[8 * 32], sB1[32], sW2[32 * 16], sB2[16], sW3[16 * 16], sB3[16];
  for (int t = threadIdx.x; t < 256; t += blockDim.x) { sW1[t] = w1[t]; sW3[t] = w3[t]; }
  for (int t = threadIdx.x; t < 512; t += blockDim.x) sW2[t] = w2[t];
  for (int t = threadIdx.x; t < 32; t += blockDim.x) sB1[t] = b1[t];
  for (int t = threadIdx.x; t < 16; t += blockDim.x) { sB2[t] = b2[t]; sB3[t] = b3[t]; }
  __syncthreads();
  int i = blockIdx.x * blockDim.x + threadIdx.x;
  if (i >= N) return;
  float dinv = rsqrtf((float)(deg[i] + 1u));
  float a[8];
  const float4* accp = reinterpret_cast<const float4*>(acc + (size_t)i * 8);
  const float4* hsp = reinterpret_cast<const float4*>(hs + (size_t)i * 8);
  float4 a0 = accp[0], a1 = accp[1], s0 = hsp[0], s1 = hsp[1];
  a[0] = dinv * (a0.x + s0.x); a[1] = dinv * (a0.y + s0.y);
  a[2] = dinv * (a0.z + s0.z); a[3] = dinv * (a0.w + s0.w);
  a[4] = dinv * (a1.x + s1.x); a[5] = dinv * (a1.y + s1.y);
  a[6] = dinv * (a1.z + s1.z); a[7] = dinv * (a1.w + s1.w);
  float h1[32];
  #pragma unroll
  for (int o = 0; o < 32; o++) {
    float s = sB1[o];
    #pragma unroll
    for (int k = 0; k < 8; k++) s = fmaf(a[k], sW1[k * 32 + o], s);
    h1[o] = fmaxf(s, 0.f);
  }
  float h2[16];
  #pragma unroll
  for (int o = 0; o < 16; o++) {
    float s = sB2[o];
    #pragma unroll
    for (int k = 0; k < 32; k++) s = fmaf(h1[k], sW2[k * 16 + o], s);
    h2[o] = fmaxf(s, 0.f);
  }
  float o0[16];
  #pragma unroll
  for (int o = 0; o < 16; o++) {
    float s = sB3[o];
    #pragma unroll
    for (int k = 0; k < 16; k++) s = fmaf(h2[k], sW3[k * 16 + o], s);
    o0[o] = s;
  }
  float4* op = reinterpret_cast<float4*>(xn + (size_t)i * 16);
  #pragma unroll
  for (int q = 0; q < 4; q++)
    op[q] = make_float4(o0[q * 4], o0[q * 4 + 1], o0[q * 4 + 2], o0[q * 4 + 3]);
}

__global__ void __launch_bounds__(256)
k_pool(const float* __restrict__ x, const float* __restrict__ xn,
       const int* __restrict__ batch, float* __restrict__ pool, int N) {
  int g = blockIdx.x;
  int lo = lowerb(batch, N, g);
  int hi = lowerb(batch, N, g + 1);
  int c = threadIdx.x & 31;
  int j = threadIdx.x >> 5;
  float s = 0.f;
  for (int n = lo + j; n < hi; n += 8) {
    s += (c < 16) ? x[(size_t)n * 16 + c] : xn[(size_t)n * 16 + (c - 16)];
  }
  __shared__ float red[8][33];
  red[j][c] = s;
  __syncthreads();
  if (threadIdx.x < 32) {
    float t = 0.f;
    #pragma unroll
    for (int q = 0; q < 8; q++) t += red[q][threadIdx.x];
    pool[(size_t)g * 32 + threadIdx.x] = t;
  }
}

__global__ void __launch_bounds__(256)
k_dag(const float* __restrict__ pool,
      const float* __restrict__ w1, const float* __restrict__ b1,
      const float* __restrict__ w2, const float* __restrict__ b2,
      const float* __restrict__ w3, const float* __restrict__ b3,
      float* __restrict__ y, int G) {
  __shared__ float sW1[32 * 32], sB1[32], sW2[32 * 16], sB2[16], sW3[16 * 16], sB3[16];
  for (int t = threadIdx.x; t < 1024; t += blockDim.x) sW1[t] = w1[t];
  for (int t = threadIdx.x; t < 512; t += blockDim.x) sW2[t] = w2[t];
  for (int t = threadIdx.x; t < 256; t += blockDim.x) sW3[t] = w3[t];
  for (int t = threadIdx.x; t < 32; t += blockDim.x) sB1[t] = b1[t];
  for (int t = threadIdx.x; t < 16; t += blockDim.x) { sB2[t] = b2[t]; sB3[t] = b3[t]; }
  __syncthreads();
  int g = blockIdx.x * blockDim.x + threadIdx.x;
  if (g >= G) return;
  float in[32];
  const float4* pp = reinterpret_cast<const float4*>(pool + (size_t)g * 32);
  #pragma unroll
  for (int q = 0; q < 8; q++) {
    float4 v = pp[q];
    in[q * 4 + 0] = v.x; in[q * 4 + 1] = v.y; in[q * 4 + 2] = v.z; in[q * 4 + 3] = v.w;
  }
  float h1[32];
  #pragma unroll
  for (int o = 0; o < 32; o++) {
    float s = sB1[o];
    #pragma unroll
    for (int k = 0; k < 32; k++) s = fmaf(in[k], sW1[k * 32 + o], s);
    h1[o] = fmaxf(s, 0.f);
  }
  float h2[16];
  #pragma unroll
  for (int o = 0; o < 16; o++) {
    float s = sB2[o];
    #pragma unroll
    for (int k = 0; k < 32; k++) s = fmaf(h1[k], sW2[k * 16 + o], s);
    h2[o] = fmaxf(s, 0.f);
  }
  float o0[16];
  #pragma unroll
  for (int o = 0; o < 16; o++) {
    float s = sB3[o];
    #pragma unroll
    for (int k = 0; k < 16; k++) s = fmaf(h2[k], sW3[k * 16 + o], s);
    o0[o] = s;
  }
  float4* yp = reinterpret_cast<float4*>(y + (size_t)g * 16);
  #pragma unroll
  for (int q = 0; q < 4; q++)
    yp[q] = make_float4(o0[q * 4], o0[q * 4 + 1], o0[q * 4 + 2], o0[q * 4 + 3]);
}

// ---------------------------------------------------------------------------

extern "C" void kernel_launch(void* const* d_in, const int* in_sizes, int n_in,
                              void* d_out, int out_size, void* d_ws, size_t ws_size,
                              hipStream_t stream) {
  const float* x = (const float*)d_in[0];
  const int* ei = (const int*)d_in[1];
  const int* batch = (const int*)d_in[2];
  const float* m1w1 = (const float*)d_in[4];  const float* m1b1 = (const float*)d_in[5];
  const float* m1w2 = (const float*)d_in[6];  const float* m1b2 = (const float*)d_in[7];
  const float* m1w3 = (const float*)d_in[8];  const float* m1b3 = (const float*)d_in[9];
  const float* m2w1 = (const float*)d_in[10]; const float* m2b1 = (const float*)d_in[11];
  const float* m2w2 = (const float*)d_in[12]; const float* m2b2 = (const float*)d_in[13];
  const float* m2w3 = (const float*)d_in[14]; const float* m2b3 = (const float*)d_in[15];
  const float* mdw1 = (const float*)d_in[16]; const float* mdb1 = (const float*)d_in[17];
  const float* mdw2 = (const float*)d_in[18]; const float* mdb2 = (const float*)d_in[19];
  const float* mdw3 = (const float*)d_in[20]; const float* mdb3 = (const float*)d_in[21];
  const float* mgw1 = (const float*)d_in[22]; const float* mgb1 = (const float*)d_in[23];
  const float* mgw2 = (const float*)d_in[24]; const float* mgb2 = (const float*)d_in[25];
  const float* mgw3 = (const float*)d_in[26]; const float* mgb3 = (const float*)d_in[27];

  int N = in_sizes[0] / 16;
  int E = in_sizes[1] / 2;
  int G = (out_size - N * 16 - 16) / 16;
  const int* rowp = ei;       // aggregation (destination) index
  const int* colp = ei + E;   // message source index

  float* xn = (float*)d_out;
  float* yv = xn + (size_t)N * 16;
  float* zv = yv + (size_t)G * 16;

  int nb = (N + BSZ - 1) / BSZ;
  int NT = (E + TSZ - 1) / TSZ;
  int NBP = (nb + 63) & ~63;
  int CSZ = (NT + CH - 1) / CH;

  size_t off = 0;
  auto alloc = [&](size_t bytes) -> size_t {
    off = (off + 255) & ~(size_t)255;
    size_t o = off; off += bytes; return o;
  };
  char* ws = (char*)d_ws;
  size_t o_deg  = alloc((size_t)N * 4);
  size_t o_hs16 = alloc((size_t)N * 16);
  size_t o_cnt  = alloc((size_t)4 * NBMAX * 4);          // tot_r, offs_r, tot_c, offs_c
  size_t o_Hr   = alloc((size_t)NT * NBP * 4);
  size_t o_Hc   = alloc((size_t)NT * NBP * 4);
  size_t o_S    = alloc((size_t)2 * CH * NBP * 4);
  size_t o_eb   = alloc(((size_t)E + 4 * NBMAX) * 4);    // padded row buckets
  size_t o_eb2  = alloc((size_t)E * 2);
  size_t o_pool = alloc((size_t)G * 32 * 4);             // fallback only
  size_t need = off;

  bool bucketed = (ws_size >= need) && (nb <= NBMAX) && (N <= (1 << 18));

  if (bucketed) {
    unsigned* deg = (unsigned*)(ws + o_deg);
    uint4* hs16 = (uint4*)(ws + o_hs16);
    unsigned* tot_r  = (unsigned*)(ws + o_cnt);
    unsigned* offs_r = tot_r + NBMAX;
    unsigned* tot_c  = tot_r + 2 * NBMAX;
    unsigned* offs_c = tot_r + 3 * NBMAX;
    unsigned* Hr = (unsigned*)(ws + o_Hr);
    unsigned* Hc = (unsigned*)(ws + o_Hc);
    unsigned* Sr = (unsigned*)(ws + o_S);
    unsigned* Sc = Sr + CH * NBP;
    unsigned* ebuf = (unsigned*)(ws + o_eb);
    unsigned short* ebuf2 = (unsigned short*)(ws + o_eb2);

    int gcol = (CH * NBP + 255) / 256;
    k_hist<<<NT, 256, 0, stream>>>(rowp, colp, E, NBP, Hr, Hc);
    k_colsum2<<<2 * gcol, 256, 0, stream>>>(Hr, Sr, Hc, Sc, NT, NBP, CSZ, gcol);
    k_colapply2<<<2 * gcol, 256, 0, stream>>>(Hr, Sr, tot_r, Hc, Sc, tot_c,
                                              NT, NBP, nb, CSZ, gcol);
    k_scan2<<<2, 1024, 0, stream>>>(tot_r, offs_r, tot_c, offs_c, nb);
    k_scat2<<<NT, 512, 0, stream>>>(rowp, colp, E, nb, NBP, Hr, Hc,
                                    offs_r, offs_c, ebuf, ebuf2);
    k_degm<<<nb, 256, 0, stream>>>(ebuf2, offs_c, tot_c, x,
                                   m1w1, m1b1, m1w2, m1b2, m1w3, m1b3,
                                   deg, hs16, N);
    k_agg<<<nb, 512, 0, stream>>>(ebuf, offs_r, tot_r, hs16, deg,
                                  m2w1, m2b1, m2w2, m2b2, m2w3, m2b3, xn, N);
    k_poold<<<G, 256, 0, stream>>>(x, xn, batch,
                                   mdw1, mdb1, mdw2, mdb2, mdw3, mdb3, yv, N);
    k_z<<<1, 256, 0, stream>>>(yv, mgw1, mgb1, mgw2, mgb2, mgw3, mgb3, zv, G);
  } else {
    unsigned* deg = (unsigned*)ws;
    float* acc = (float*)(ws + (size_t)N * 4);
    float* hs  = (float*)(ws + (size_t)N * 36);
    float* pool = (float*)(ws + (size_t)N * 68);

    hipMemsetAsync(ws, 0, (size_t)N * 36, stream);
    const int TB = 256;
    k_deg_atomic<<<(E + TB - 1) / TB, TB, 0, stream>>>(colp, deg, E);
    k_mlp1f<<<(N + TB - 1) / TB, TB, 0, stream>>>(x, deg, m1w1, m1b1, m1w2, m1b2, m1w3, m1b3, hs, N);
    k_scatter_atomic<<<(E + TB - 1) / TB, TB, 0, stream>>>(rowp, colp, hs, acc, E);
    k_finalize<<<(N + TB - 1) / TB, TB, 0, stream>>>(hs, acc, deg, m2w1, m2b1, m2w2, m2b2, m2w3, m2b3, xn, N);
    k_pool<<<G, TB, 0, stream>>>(x, xn, batch, pool, N);
    k_dag<<<(G + TB - 1) / TB, TB, 0, stream>>>(pool, mdw1, mdb1, mdw2, mdb2, mdw3, mdb3, yv, G);
    k_z<<<1, TB, 0, stream>>>(yv, mgw1, mgb1, mgw2, mgb2, mgw3, mgb3, zv, G);
  }
}

// Round 12
// 230.956 us; speedup vs baseline: 1.2263x; 1.2263x over previous
//
#include <hip/hip_runtime.h>
#include <hip/hip_fp16.h>

// ---------------------------------------------------------------------------
// GraphEncoderNetwork: GCNConv(mlp1 -> norm scatter -> mlp2) + pooled mlp_dag
// + global mlp. All fp32. N=200000, E=6400000, G=1000, IN=16, D=16.
//
// Round 12: r11's balanced-slice k_agg regressed (serial cum-walk + killed
// gather ILP). Revert accumulate to r10's 2-thread/node + end-of-kernel
// stage combine; KEEP r11's wave-0 shfl scan (4 barriers/chunk vs 16),
// 512-thread k_scat2, and fused k_poold.
// ---------------------------------------------------------------------------

#define BSH 8               // bucket shift
#define BSZ 256             // nodes per bucket
#define NBMAX 1024          // max buckets (N <= 2^18)
#define TSZ 4096            // edges per partition tile
#define ATSZ 8192           // edges per k_agg sort chunk
#define CH 16               // chunks per column scan

__device__ __forceinline__ int lowerb(const int* __restrict__ b, int n, int v) {
  int lo = 0, hi = n;
  while (lo < hi) { int m = (lo + hi) >> 1; if (b[m] < v) lo = m + 1; else hi = m; }
  return lo;
}

__device__ __forceinline__ void addmsg(float* acc, uint4 g) {
  const __half2* h2 = reinterpret_cast<const __half2*>(&g);
  #pragma unroll
  for (int q = 0; q < 4; q++) {
    float2 f = __half22float2(h2[q]);
    acc[2 * q] += f.x;
    acc[2 * q + 1] += f.y;
  }
}

// ---------------- bucketing machinery (atomic-free partition) --------------

// per-tile histogram of row and col keys -> Hr[t][b], Hc[t][b]
__global__ void __launch_bounds__(256)
k_hist(const int* __restrict__ row, const int* __restrict__ col, int E,
       int NBP, unsigned* __restrict__ Hr, unsigned* __restrict__ Hc) {
  __shared__ unsigned hr[NBMAX], hc[NBMAX];
  int t = threadIdx.x;
  int base = blockIdx.x * TSZ;
  int cnt = min(TSZ, E - base);
  for (int i = t; i < NBP; i += 256) { hr[i] = 0; hc[i] = 0; }
  __syncthreads();
  #pragma unroll
  for (int u = 0; u < 4; u++) {
    int idx = base + 4 * (t + 256 * u);
    unsigned rv[4], cv[4];
    if (idx + 3 < E) {
      uint4 r4 = *reinterpret_cast<const uint4*>(row + idx);
      uint4 c4 = *reinterpret_cast<const uint4*>(col + idx);
      rv[0] = r4.x; rv[1] = r4.y; rv[2] = r4.z; rv[3] = r4.w;
      cv[0] = c4.x; cv[1] = c4.y; cv[2] = c4.z; cv[3] = c4.w;
    } else {
      #pragma unroll
      for (int j = 0; j < 4; j++) {
        bool v = (idx + j) < E;
        rv[j] = v ? (unsigned)row[idx + j] : 0u;
        cv[j] = v ? (unsigned)col[idx + j] : 0u;
      }
    }
    int l0 = 4 * (t + 256 * u);
    #pragma unroll
    for (int j = 0; j < 4; j++) {
      if (l0 + j < cnt) {
        atomicAdd(&hr[rv[j] >> BSH], 1u);
        atomicAdd(&hc[cv[j] >> BSH], 1u);
      }
    }
  }
  __syncthreads();
  size_t rb = (size_t)blockIdx.x * NBP;
  for (int i = t; i < NBP; i += 256) {
    Hr[rb + i] = hr[i];
    Hc[rb + i] = hc[i];
  }
}

// chunk sums per bucket column (row half then col half of the grid)
__global__ void __launch_bounds__(256)
k_colsum2(const unsigned* __restrict__ Hr, unsigned* __restrict__ Sr,
          const unsigned* __restrict__ Hc, unsigned* __restrict__ Sc,
          int NT, int NBP, int CSZ, int gcol) {
  int blk = blockIdx.x;
  const unsigned* H = Hr; unsigned* S = Sr;
  if (blk >= gcol) { blk -= gcol; H = Hc; S = Sc; }
  int i = blk * 256 + threadIdx.x;
  if (i >= CH * NBP) return;
  int ch = i / NBP, b = i - ch * NBP;
  int t0 = ch * CSZ, t1 = min(NT, t0 + CSZ);
  unsigned s = 0;
  for (int t = t0; t < t1; t++) s += H[(size_t)t * NBP + b];
  S[i] = s;
}

// in-place exclusive prefix over tiles per bucket; emit per-bucket totals
__global__ void __launch_bounds__(256)
k_colapply2(unsigned* __restrict__ Hr, const unsigned* __restrict__ Sr,
            unsigned* __restrict__ tot_r,
            unsigned* __restrict__ Hc, const unsigned* __restrict__ Sc,
            unsigned* __restrict__ tot_c,
            int NT, int NBP, int nb, int CSZ, int gcol) {
  int blk = blockIdx.x;
  unsigned* H = Hr; const unsigned* S = Sr; unsigned* tot = tot_r;
  if (blk >= gcol) { blk -= gcol; H = Hc; S = Sc; tot = tot_c; }
  int i = blk * 256 + threadIdx.x;
  if (i >= CH * NBP) return;
  int ch = i / NBP, b = i - ch * NBP;
  unsigned run = 0;
  for (int c = 0; c < ch; c++) run += S[c * NBP + b];
  int t0 = ch * CSZ, t1 = min(NT, t0 + CSZ);
  for (int t = t0; t < t1; t++) {
    unsigned v = H[(size_t)t * NBP + b];
    H[(size_t)t * NBP + b] = run;
    run += v;
  }
  if (ch == CH - 1 && b < nb) tot[b] = run;
}

// fused scan over dense totals: block 0 row (pad x4), block 1 col
__global__ void __launch_bounds__(1024)
k_scan2(const unsigned* __restrict__ tot_r, unsigned* __restrict__ offs_r,
        const unsigned* __restrict__ tot_c, unsigned* __restrict__ offs_c,
        int nb) {
  const unsigned* tot = blockIdx.x ? tot_c : tot_r;
  unsigned* offs = blockIdx.x ? offs_c : offs_r;
  unsigned pm1 = blockIdx.x ? 0u : 3u;
  __shared__ unsigned s[1024];
  int t = threadIdx.x;
  unsigned e0 = (2 * t < nb) ? ((tot[2 * t] + pm1) & ~pm1) : 0u;
  unsigned e1 = (2 * t + 1 < nb) ? ((tot[2 * t + 1] + pm1) & ~pm1) : 0u;
  unsigned sum = e0 + e1;
  s[t] = sum;
  __syncthreads();
  for (int d = 1; d < 1024; d <<= 1) {
    unsigned v = (t >= d) ? s[t - d] : 0u;
    __syncthreads();
    s[t] += v;
    __syncthreads();
  }
  unsigned ex = s[t] - sum;
  if (2 * t < nb)     offs[2 * t] = ex;
  if (2 * t + 1 < nb) offs[2 * t + 1] = ex + e0;
}

// tile-local LDS reorder scatter, fused hist+rank, deterministic bases,
// 512 threads, 2-level wave scan
__global__ void __launch_bounds__(512)
k_scat2(const int* __restrict__ row, const int* __restrict__ col, int E, int nb,
        int NBP,
        const unsigned* __restrict__ Hr, const unsigned* __restrict__ Hc,
        const unsigned* __restrict__ offs_r, const unsigned* __restrict__ offs_c,
        unsigned* __restrict__ ebuf, unsigned short* __restrict__ ebuf2) {
  __shared__ unsigned buf[TSZ];            // 16KB reordered payloads
  __shared__ unsigned short bkt[TSZ];      // 8KB bucket id per slot
  __shared__ unsigned h[NBMAX], diff[NBMAX];  // 8KB
  __shared__ unsigned wtot[4];
  int t = threadIdx.x;
  int base = blockIdx.x * TSZ;
  int cnt = min(TSZ, E - base);
  size_t hrow = (size_t)blockIdx.x * NBP;

  unsigned rv[8], cv[8];
  #pragma unroll
  for (int u = 0; u < 2; u++) {
    int idx = base + 4 * (t + 512 * u);
    if (idx + 3 < E) {
      uint4 r4 = *reinterpret_cast<const uint4*>(row + idx);
      uint4 c4 = *reinterpret_cast<const uint4*>(col + idx);
      rv[4*u] = r4.x; rv[4*u+1] = r4.y; rv[4*u+2] = r4.z; rv[4*u+3] = r4.w;
      cv[4*u] = c4.x; cv[4*u+1] = c4.y; cv[4*u+2] = c4.z; cv[4*u+3] = c4.w;
    } else {
      #pragma unroll
      for (int j = 0; j < 4; j++) {
        bool v = (idx + j) < E;
        rv[4*u+j] = v ? (unsigned)row[idx + j] : 0u;
        cv[4*u+j] = v ? (unsigned)col[idx + j] : 0u;
      }
    }
  }

  // ================= ROW PASS =================
  for (int i = t; i < NBMAX; i += 512) h[i] = 0;
  __syncthreads();
  unsigned rk[8];
  #pragma unroll
  for (int u = 0; u < 2; u++) {
    int l0 = 4 * (t + 512 * u);
    #pragma unroll
    for (int j = 0; j < 4; j++)
      if (l0 + j < cnt) rk[4*u+j] = atomicAdd(&h[rv[4*u+j] >> BSH], 1u);
  }
  __syncthreads();
  unsigned a0 = 0, a1 = 0, a2 = 0, a3 = 0, p1 = 0, p2 = 0, p3 = 0, isum = 0;
  if (t < 256) {
    a0 = h[4*t]; a1 = h[4*t+1]; a2 = h[4*t+2]; a3 = h[4*t+3];
    p1 = a0 + a1; p2 = p1 + a2; p3 = p2 + a3;
    isum = p3;
    #pragma unroll
    for (int d = 1; d < 64; d <<= 1) {
      unsigned o = __shfl_up(isum, d, 64);
      if ((t & 63) >= d) isum += o;
    }
    if ((t & 63) == 63) wtot[t >> 6] = isum;
  }
  __syncthreads();
  if (t < 256) {
    unsigned woff = 0;
    for (int w = 0; w < (t >> 6); w++) woff += wtot[w];
    unsigned ex = woff + isum - p3;
    unsigned l[4] = {ex, ex + a0, ex + p1, ex + p2};
    #pragma unroll
    for (int k = 0; k < 4; k++) {
      int b = 4 * t + k;
      h[b] = l[k];
      if (b < nb) diff[b] = offs_r[b] + Hr[hrow + b] - l[k];
    }
  }
  __syncthreads();
  #pragma unroll
  for (int u = 0; u < 2; u++) {
    int l0 = 4 * (t + 512 * u);
    #pragma unroll
    for (int j = 0; j < 4; j++) {
      if (l0 + j < cnt) {
        unsigned r = rv[4*u+j], b = r >> BSH;
        unsigned pos = h[b] + rk[4*u+j];
        buf[pos] = ((r & (BSZ - 1u)) << 18) | cv[4*u+j];
        bkt[pos] = (unsigned short)b;
      }
    }
  }
  __syncthreads();
  #pragma unroll
  for (int u = 0; u < 8; u++) {
    int s2 = t + 512 * u;
    if (s2 < cnt) ebuf[(unsigned)s2 + diff[bkt[s2]]] = buf[s2];
  }
  __syncthreads();

  // ================= COL PASS =================
  for (int i = t; i < NBMAX; i += 512) h[i] = 0;
  __syncthreads();
  #pragma unroll
  for (int u = 0; u < 2; u++) {
    int l0 = 4 * (t + 512 * u);
    #pragma unroll
    for (int j = 0; j < 4; j++)
      if (l0 + j < cnt) rk[4*u+j] = atomicAdd(&h[cv[4*u+j] >> BSH], 1u);
  }
  __syncthreads();
  a0 = a1 = a2 = a3 = p1 = p2 = p3 = isum = 0;
  if (t < 256) {
    a0 = h[4*t]; a1 = h[4*t+1]; a2 = h[4*t+2]; a3 = h[4*t+3];
    p1 = a0 + a1; p2 = p1 + a2; p3 = p2 + a3;
    isum = p3;
    #pragma unroll
    for (int d = 1; d < 64; d <<= 1) {
      unsigned o = __shfl_up(isum, d, 64);
      if ((t & 63) >= d) isum += o;
    }
    if ((t & 63) == 63) wtot[t >> 6] = isum;
  }
  __syncthreads();
  if (t < 256) {
    unsigned woff = 0;
    for (int w = 0; w < (t >> 6); w++) woff += wtot[w];
    unsigned ex = woff + isum - p3;
    unsigned l[4] = {ex, ex + a0, ex + p1, ex + p2};
    #pragma unroll
    for (int k = 0; k < 4; k++) {
      int b = 4 * t + k;
      h[b] = l[k];
      if (b < nb) diff[b] = offs_c[b] + Hc[hrow + b] - l[k];
    }
  }
  __syncthreads();
  #pragma unroll
  for (int u = 0; u < 2; u++) {
    int l0 = 4 * (t + 512 * u);
    #pragma unroll
    for (int j = 0; j < 4; j++) {
      if (l0 + j < cnt) {
        unsigned c = cv[4*u+j], b = c >> BSH;
        unsigned pos = h[b] + rk[4*u+j];
        buf[pos] = c & (BSZ - 1u);
        bkt[pos] = (unsigned short)b;
      }
    }
  }
  __syncthreads();
  #pragma unroll
  for (int u = 0; u < 8; u++) {
    int s2 = t + 512 * u;
    if (s2 < cnt) ebuf2[(unsigned)s2 + diff[bkt[s2]]] = (unsigned short)buf[s2];
  }
}

// ---------------- fused degree + mlp1 --------------------------------------

__global__ void __launch_bounds__(256)
k_degm(const unsigned short* __restrict__ eb, const unsigned* __restrict__ offs_c,
       const unsigned* __restrict__ tot_c,
       const float* __restrict__ x,
       const float* __restrict__ w1, const float* __restrict__ b1,
       const float* __restrict__ w2, const float* __restrict__ b2,
       const float* __restrict__ w3, const float* __restrict__ b3,
       unsigned* __restrict__ deg, uint4* __restrict__ hs16, int N) {
  __shared__ unsigned cnt[BSZ];
  __shared__ float sW1[16 * 32], sB1[32], sW2[32 * 16], sB2[16], sW3[16 * 8], sB3[8];
  int b = blockIdx.x, t = threadIdx.x;
  cnt[t] = 0;
  sW1[t] = w1[t]; sW1[t + 256] = w1[t + 256];
  sW2[t] = w2[t]; sW2[t + 256] = w2[t + 256];
  if (t < 128) sW3[t] = w3[t];
  if (t < 32) sB1[t] = b1[t];
  if (t < 16) sB2[t] = b2[t];
  if (t < 8) sB3[t] = b3[t];
  __syncthreads();
  unsigned s = offs_c[b], n = tot_c[b];
  for (unsigned i = t; i < n; i += 256) atomicAdd(&cnt[eb[s + i]], 1u);
  __syncthreads();
  int node = b * BSZ + t;
  if (node >= N) return;
  unsigned d = cnt[t];
  deg[node] = d;

  float xin[16];
  const float4* xp = reinterpret_cast<const float4*>(x + (size_t)node * 16);
  #pragma unroll
  for (int q = 0; q < 4; q++) {
    float4 v = xp[q];
    xin[q * 4 + 0] = v.x; xin[q * 4 + 1] = v.y; xin[q * 4 + 2] = v.z; xin[q * 4 + 3] = v.w;
  }
  float h1[32];
  #pragma unroll
  for (int o = 0; o < 32; o++) {
    float s1 = sB1[o];
    #pragma unroll
    for (int k = 0; k < 16; k++) s1 = fmaf(xin[k], sW1[k * 32 + o], s1);
    h1[o] = fmaxf(s1, 0.f);
  }
  float h2[16];
  #pragma unroll
  for (int o = 0; o < 16; o++) {
    float s1 = sB2[o];
    #pragma unroll
    for (int k = 0; k < 32; k++) s1 = fmaf(h1[k], sW2[k * 16 + o], s1);
    h2[o] = fmaxf(s1, 0.f);
  }
  float dinv = rsqrtf((float)(d + 1u));  // +1 self-loop
  float o0[8];
  #pragma unroll
  for (int o = 0; o < 8; o++) {
    float s1 = sB3[o];
    #pragma unroll
    for (int k = 0; k < 16; k++) s1 = fmaf(h2[k], sW3[k * 8 + o], s1);
    o0[o] = dinv * s1;
  }
  __half2 hh[4];
  #pragma unroll
  for (int q = 0; q < 4; q++) hh[q] = __floats2half2_rn(o0[2 * q], o0[2 * q + 1]);
  hs16[node] = *reinterpret_cast<const uint4*>(hh);
}

// ---------------- aggregation (512 thr, r10 accumulate + wave scan) --------

__global__ void __launch_bounds__(512)
k_agg(const unsigned* __restrict__ ebuf, const unsigned* __restrict__ offs,
      const unsigned* __restrict__ tot,
      const uint4* __restrict__ hs16, const unsigned* __restrict__ deg,
      const float* __restrict__ w1, const float* __restrict__ b1,
      const float* __restrict__ w2, const float* __restrict__ b2,
      const float* __restrict__ w3, const float* __restrict__ b3,
      float* __restrict__ xn, int N) {
  __shared__ unsigned sorted[ATSZ];        // 32KB
  __shared__ unsigned hist[256];
  __shared__ unsigned cum[257];
  __shared__ float stage[BSZ][9];          // 9KB, pad 9 vs bank conflicts
  __shared__ float sW1[256], sB1[32], sW2[512], sB2[16], sW3[256], sB3[16];
  int t = threadIdx.x;
  if (t < 256) { sW1[t] = w1[t]; sW3[t] = w3[t]; }
  else { int u = t - 256; sW2[u] = w2[u]; sW2[u + 256] = w2[u + 256]; }
  if (t < 32) sB1[t] = b1[t];
  if (t < 16) { sB2[t] = b2[t]; sB3[t] = b3[t]; }

  int b = blockIdx.x;
  unsigned s = offs[b], n = tot[b];
  unsigned nr = (n + 3u) & ~3u;            // padded region is allocated

  float acc[8];
  #pragma unroll
  for (int c = 0; c < 8; c++) acc[c] = 0.f;
  int nl = t >> 1, half = t & 1;

  for (unsigned c0 = 0; c0 < n; c0 += ATSZ) {
    if (t < 256) hist[t] = 0;
    __syncthreads();

    unsigned rel[16], colv[16], rk[16];
    #pragma unroll
    for (int u = 0; u < 4; u++) {
      unsigned idx = c0 + 4 * (unsigned)(t + 512 * u);
      uint4 pk = make_uint4(0u, 0u, 0u, 0u);
      if (idx < nr) pk = *reinterpret_cast<const uint4*>(ebuf + s + idx);
      #pragma unroll
      for (int j = 0; j < 4; j++) {
        bool real = (idx + j) < n;
        unsigned p = (&pk.x)[j];
        rel[4*u+j]  = real ? (p >> 18) : 256u;     // 256 = sentinel
        colv[4*u+j] = p & 0x3FFFFu;
      }
    }
    // fused hist+rank
    #pragma unroll
    for (int u = 0; u < 16; u++)
      if (rel[u] < 256u) rk[u] = atomicAdd(&hist[rel[u]], 1u);
    __syncthreads();
    // wave-0 scan of 256 bins (4 bins/lane, shfl inclusive scan)
    if (t < 64) {
      unsigned v0 = hist[4*t], v1 = hist[4*t+1], v2 = hist[4*t+2], v3 = hist[4*t+3];
      unsigned q1 = v0 + v1, q2 = q1 + v2, q3 = q2 + v3;
      unsigned isum = q3;
      #pragma unroll
      for (int d = 1; d < 64; d <<= 1) {
        unsigned o = __shfl_up(isum, d, 64);
        if (t >= d) isum += o;
      }
      unsigned ex = isum - q3;
      cum[4*t] = ex; cum[4*t+1] = ex + v0; cum[4*t+2] = ex + q1; cum[4*t+3] = ex + q2;
      if (t == 63) cum[256] = isum;
    }
    __syncthreads();
    #pragma unroll
    for (int u = 0; u < 16; u++) {
      if (rel[u] < 256u) sorted[cum[rel[u]] + rk[u]] = colv[u];
    }
    __syncthreads();
    // register accumulation: 2 threads per node, contiguous halves
    unsigned lo = cum[nl], hi = cum[nl + 1];
    unsigned len = hi - lo, mid = lo + (len >> 1);
    unsigned i = half ? mid : lo;
    unsigned e = half ? hi : mid;
    for (; i + 4 <= e; i += 4) {
      unsigned q0 = sorted[i], q1 = sorted[i + 1], q2 = sorted[i + 2], q3 = sorted[i + 3];
      uint4 g0 = hs16[q0];
      uint4 g1 = hs16[q1];
      uint4 g2 = hs16[q2];
      uint4 g3 = hs16[q3];
      addmsg(acc, g0); addmsg(acc, g1); addmsg(acc, g2); addmsg(acc, g3);
    }
    for (; i < e; i++) { uint4 g = hs16[sorted[i]]; addmsg(acc, g); }
    __syncthreads();
  }

  // combine halves (barrier-ordered, no atomics)
  if (!half) {
    #pragma unroll
    for (int c = 0; c < 8; c++) stage[nl][c] = acc[c];
  }
  __syncthreads();
  if (half) {
    #pragma unroll
    for (int c = 0; c < 8; c++) stage[nl][c] += acc[c];
  }
  __syncthreads();

  if (t >= 256) return;
  int node = b * BSZ + t;
  if (node >= N) return;
  float dinv = rsqrtf((float)(deg[node] + 1u));
  uint4 selfp = hs16[node];
  const __half2* sh = reinterpret_cast<const __half2*>(&selfp);
  float a[8];
  #pragma unroll
  for (int q = 0; q < 4; q++) {
    float2 f = __half22float2(sh[q]);
    a[2 * q]     = dinv * (stage[t][2 * q] + f.x);
    a[2 * q + 1] = dinv * (stage[t][2 * q + 1] + f.y);
  }

  float h1[32];
  #pragma unroll
  for (int o = 0; o < 32; o++) {
    float v = sB1[o];
    #pragma unroll
    for (int k = 0; k < 8; k++) v = fmaf(a[k], sW1[k * 32 + o], v);
    h1[o] = fmaxf(v, 0.f);
  }
  float h2v[16];
  #pragma unroll
  for (int o = 0; o < 16; o++) {
    float v = sB2[o];
    #pragma unroll
    for (int k = 0; k < 32; k++) v = fmaf(h1[k], sW2[k * 16 + o], v);
    h2v[o] = fmaxf(v, 0.f);
  }
  float o0[16];
  #pragma unroll
  for (int o = 0; o < 16; o++) {
    float v = sB3[o];
    #pragma unroll
    for (int k = 0; k < 16; k++) v = fmaf(h2v[k], sW3[k * 16 + o], v);
    o0[o] = v;
  }
  float4* op = reinterpret_cast<float4*>(xn + (size_t)node * 16);
  #pragma unroll
  for (int q = 0; q < 4; q++)
    op[q] = make_float4(o0[q * 4], o0[q * 4 + 1], o0[q * 4 + 2], o0[q * 4 + 3]);
}

// ---------------- fused pool + mlp_dag -------------------------------------

__global__ void __launch_bounds__(256)
k_poold(const float* __restrict__ x, const float* __restrict__ xn,
        const int* __restrict__ batch,
        const float* __restrict__ w1, const float* __restrict__ b1,
        const float* __restrict__ w2, const float* __restrict__ b2,
        const float* __restrict__ w3, const float* __restrict__ b3,
        float* __restrict__ y, int N) {
  __shared__ float red[8][33];
  __shared__ float pv[32], h1s[32];
  __shared__ float sW1[1024], sW2[512], sW3[256], sB1[32], sB2[16], sB3[16];
  int t = threadIdx.x;
  for (int i = t; i < 1024; i += 256) sW1[i] = w1[i];
  for (int i = t; i < 512; i += 256) sW2[i] = w2[i];
  if (t < 256) sW3[t] = w3[t];
  if (t < 32) sB1[t] = b1[t];
  if (t < 16) { sB2[t] = b2[t]; sB3[t] = b3[t]; }

  int g = blockIdx.x;
  int lo = lowerb(batch, N, g);
  int hi = lowerb(batch, N, g + 1);
  int c = t & 31;
  int j = t >> 5;
  float s = 0.f;
  for (int n = lo + j; n < hi; n += 8) {
    s += (c < 16) ? x[(size_t)n * 16 + c] : xn[(size_t)n * 16 + (c - 16)];
  }
  red[j][c] = s;
  __syncthreads();
  if (t < 32) {
    float v = 0.f;
    #pragma unroll
    for (int q = 0; q < 8; q++) v += red[q][t];
    pv[t] = v;
  }
  __syncthreads();
  if (t < 32) {
    float s1 = sB1[t];
    #pragma unroll
    for (int k = 0; k < 32; k++) s1 = fmaf(pv[k], sW1[k * 32 + t], s1);
    h1s[t] = fmaxf(s1, 0.f);
  }
  __syncthreads();
  if (t < 16) {
    float s2 = sB2[t];
    #pragma unroll
    for (int k = 0; k < 32; k++) s2 = fmaf(h1s[k], sW2[k * 16 + t], s2);
    float h2 = fmaxf(s2, 0.f);
    red[0][t] = h2;   // reuse red row as h2 store
  }
  __syncthreads();
  if (t < 16) {
    float s3 = sB3[t];
    #pragma unroll
    for (int k = 0; k < 16; k++) s3 = fmaf(red[0][k], sW3[k * 16 + t], s3);
    y[(size_t)g * 16 + t] = s3;
  }
}

__global__ void __launch_bounds__(256)
k_z(const float* __restrict__ y,
    const float* __restrict__ w1, const float* __restrict__ b1,
    const float* __restrict__ w2, const float* __restrict__ b2,
    const float* __restrict__ w3, const float* __restrict__ b3,
    float* __restrict__ z, int G) {
  __shared__ float red[16][17];
  __shared__ float sum[16], h1s[32], h2s[16];
  int t = threadIdx.x;
  int c = t & 15, j = t >> 4;
  float s = 0.f;
  for (int g = j; g < G; g += 16) s += y[(size_t)g * 16 + c];
  red[j][c] = s;
  __syncthreads();
  if (t < 16) {
    float v = 0.f;
    #pragma unroll
    for (int q = 0; q < 16; q++) v += red[q][t];
    sum[t] = v;
  }
  __syncthreads();
  if (t < 32) {
    float s1 = b1[t];
    #pragma unroll
    for (int k = 0; k < 16; k++) s1 = fmaf(sum[k], w1[k * 32 + t], s1);
    h1s[t] = fmaxf(s1, 0.f);
  }
  __syncthreads();
  if (t < 16) {
    float s2 = b2[t];
    #pragma unroll
    for (int k = 0; k < 32; k++) s2 = fmaf(h1s[k], w2[k * 16 + t], s2);
    h2s[t] = fmaxf(s2, 0.f);
  }
  __syncthreads();
  if (t < 16) {
    float s3 = b3[t];
    #pragma unroll
    for (int k = 0; k < 16; k++) s3 = fmaf(h2s[k], w3[k * 16 + t], s3);
    z[t] = s3;
  }
}

// ---------------- fallback (known-good atomic path) ------------------------

__global__ void k_deg_atomic(const int* __restrict__ col, unsigned* __restrict__ deg, int E) {
  int e = blockIdx.x * blockDim.x + threadIdx.x;
  if (e < E) atomicAdd(&deg[col[e]], 1u);
}

__global__ void __launch_bounds__(256)
k_mlp1f(const float* __restrict__ x, const unsigned* __restrict__ deg,
        const float* __restrict__ w1, const float* __restrict__ b1,
        const float* __restrict__ w2, const float* __restrict__ b2,
        const float* __restrict__ w3, const float* __restrict__ b3,
        float* __restrict__ hs, int N) {
  __shared__ float sW1[16 * 32], sB1[32], sW2[32 * 16], sB2[16], sW3[16 * 8], sB3[8];
  for (int t = threadIdx.x; t < 512; t += blockDim.x) { sW1[t] = w1[t]; sW2[t] = w2[t]; }
  for (int t = threadIdx.x; t < 128; t += blockDim.x) sW3[t] = w3[t];
  for (int t = threadIdx.x; t < 32; t += blockDim.x) sB1[t] = b1[t];
  for (int t = threadIdx.x; t < 16; t += blockDim.x) sB2[t] = b2[t];
  for (int t = threadIdx.x; t < 8; t += blockDim.x) sB3[t] = b3[t];
  __syncthreads();
  int i = blockIdx.x * blockDim.x + threadIdx.x;
  if (i >= N) return;
  float xin[16];
  const float4* xp = reinterpret_cast<const float4*>(x + (size_t)i * 16);
  #pragma unroll
  for (int q = 0; q < 4; q++) {
    float4 v = xp[q];
    xin[q * 4 + 0] = v.x; xin[q * 4 + 1] = v.y; xin[q * 4 + 2] = v.z; xin[q * 4 + 3] = v.w;
  }
  float h1[32];
  #pragma unroll
  for (int o = 0; o < 32; o++) {
    float s = sB1[o];
    #pragma unroll
    for (int k = 0; k < 16; k++) s = fmaf(xin[k], sW1[k * 32 + o], s);
    h1[o] = fmaxf(s, 0.f);
  }
  float h2[16];
  #pragma unroll
  for (int o = 0; o < 16; o++) {
    float s = sB2[o];
    #pragma unroll
    for (int k = 0; k < 32; k++) s = fmaf(h1[k], sW2[k * 16 + o], s);
    h2[o] = fmaxf(s, 0.f);
  }
  float dinv = rsqrtf((float)(deg[i] + 1u));
  float o0[8];
  #pragma unroll
  for (int o = 0; o < 8; o++) {
    float s = sB3[o];
    #pragma unroll
    for (int k = 0; k < 16; k++) s = fmaf(h2[k], sW3[k * 8 + o], s);
    o0[o] = dinv * s;
  }
  float4* hp = reinterpret_cast<float4*>(hs + (size_t)i * 8);
  hp[0] = make_float4(o0[0], o0[1], o0[2], o0[3]);
  hp[1] = make_float4(o0[4], o0[5], o0[6], o0[7]);
}

__global__ void k_scatter_atomic(const int* __restrict__ row, const int* __restrict__ col,
                                 const float* __restrict__ hs, float* __restrict__ acc, int E) {
  int e = blockIdx.x * blockDim.x + threadIdx.x;
  if (e >= E) return;
  int r = row[e], c = col[e];
  const float4* hp = reinterpret_cast<const float4*>(hs + (size_t)c * 8);
  float4 a = hp[0], b = hp[1];
  float* ap = acc + (size_t)r * 8;
  atomicAdd(ap + 0, a.x); atomicAdd(ap + 1, a.y);
  atomicAdd(ap + 2, a.z); atomicAdd(ap + 3, a.w);
  atomicAdd(ap + 4, b.x); atomicAdd(ap + 5, b.y);
  atomicAdd(ap + 6, b.z); atomicAdd(ap + 7, b.w);
}

__global__ void __launch_bounds__(256)
k_finalize(const float* __restrict__ hs, const float* __restrict__ acc,
           const unsigned* __restrict__ deg,
           const float* __restrict__ w1, const float* __restrict__ b1,
           const float* __restrict__ w2, const float* __restrict__ b2,
           const float* __restrict__ w3, const float* __restrict__ b3,
           float* __restrict__ xn, int N) {
  __shared__ float sW1[8 * 32], sB1[32], sW2[32 * 16], sB2[16], sW3[16 * 16], sB3[16];
  for (int t = threadIdx.x; t < 256; t += blockDim.x) { sW1[t] = w1[t]; sW3[t] = w3[t]; }
  for (int t = threadIdx.x; t < 512; t += blockDim.x) sW2[t] = w2[t];
  for (int t = threadIdx.x; t < 32; t += blockDim.x) sB1[t] = b1[t];
  for (int t = threadIdx.x; t < 16; t += blockDim.x) { sB2[t] = b2[t]; sB3[t] = b3[t]; }
  __syncthreads();
  int i = blockIdx.x * blockDim.x + threadIdx.x;
  if (i >= N) return;
  float dinv = rsqrtf((float)(deg[i] + 1u));
  float a[8];
  const float4* accp = reinterpret_cast<const float4*>(acc + (size_t)i * 8);
  const float4* hsp = reinterpret_cast<const float4*>(hs + (size_t)i * 8);
  float4 a0 = accp[0], a1 = accp[1], s0 = hsp[0], s1 = hsp[1];
  a[0] = dinv * (a0.x + s0.x); a[1] = dinv * (a0.y + s0.y);
  a[2] = dinv * (a0.z + s0.z); a[3] = dinv * (a0.w + s0.w);
  a[4] = dinv * (a1.x + s1.x); a[5] = dinv * (a1.y + s1.y);
  a[6] = dinv * (a1.z + s1.z); a[7] = dinv * (a1.w + s1.w);
  float h1[32];
  #pragma unroll
  for (int o = 0; o < 32; o++) {
    float s = sB1[o];
    #pragma unroll
    for (int k = 0; k < 8; k++) s = fmaf(a[k], sW1[k * 32 + o], s);
    h1[o] = fmaxf(s, 0.f);
  }
  float h2[16];
  #pragma unroll
  for (int o = 0; o < 16; o++) {
    float s = sB2[o];
    #pragma unroll
    for (int k = 0; k < 32; k++) s = fmaf(h1[k], sW2[k * 16 + o], s);
    h2[o] = fmaxf(s, 0.f);
  }
  float o0[16];
  #pragma unroll
  for (int o = 0; o < 16; o++) {
    float s = sB3[o];
    #pragma unroll
    for (int k = 0; k < 16; k++) s = fmaf(h2[k], sW3[k * 16 + o], s);
    o0[o] = s;
  }
  float4* op = reinterpret_cast<float4*>(xn + (size_t)i * 16);
  #pragma unroll
  for (int q = 0; q < 4; q++)
    op[q] = make_float4(o0[q * 4], o0[q * 4 + 1], o0[q * 4 + 2], o0[q * 4 + 3]);
}

__global__ void __launch_bounds__(256)
k_pool(const float* __restrict__ x, const float* __restrict__ xn,
       const int* __restrict__ batch, float* __restrict__ pool, int N) {
  int g = blockIdx.x;
  int lo = lowerb(batch, N, g);
  int hi = lowerb(batch, N, g + 1);
  int c = threadIdx.x & 31;
  int j = threadIdx.x >> 5;
  float s = 0.f;
  for (int n = lo + j; n < hi; n += 8) {
    s += (c < 16) ? x[(size_t)n * 16 + c] : xn[(size_t)n * 16 + (c - 16)];
  }
  __shared__ float red[8][33];
  red[j][c] = s;
  __syncthreads();
  if (threadIdx.x < 32) {
    float t = 0.f;
    #pragma unroll
    for (int q = 0; q < 8; q++) t += red[q][threadIdx.x];
    pool[(size_t)g * 32 + threadIdx.x] = t;
  }
}

__global__ void __launch_bounds__(256)
k_dag(const float* __restrict__ pool,
      const float* __restrict__ w1, const float* __restrict__ b1,
      const float* __restrict__ w2, const float* __restrict__ b2,
      const float* __restrict__ w3, const float* __restrict__ b3,
      float* __restrict__ y, int G) {
  __shared__ float sW1[32 * 32], sB1[32], sW2[32 * 16], sB2[16], sW3[16 * 16], sB3[16];
  for (int t = threadIdx.x; t < 1024; t += blockDim.x) sW1[t] = w1[t];
  for (int t = threadIdx.x; t < 512; t += blockDim.x) sW2[t] = w2[t];
  for (int t = threadIdx.x; t < 256; t += blockDim.x) sW3[t] = w3[t];
  for (int t = threadIdx.x; t < 32; t += blockDim.x) sB1[t] = b1[t];
  for (int t = threadIdx.x; t < 16; t += blockDim.x) { sB2[t] = b2[t]; sB3[t] = b3[t]; }
  __syncthreads();
  int g = blockIdx.x * blockDim.x + threadIdx.x;
  if (g >= G) return;
  float in[32];
  const float4* pp = reinterpret_cast<const float4*>(pool + (size_t)g * 32);
  #pragma unroll
  for (int q = 0; q < 8; q++) {
    float4 v = pp[q];
    in[q * 4 + 0] = v.x; in[q * 4 + 1] = v.y; in[q * 4 + 2] = v.z; in[q * 4 + 3] = v.w;
  }
  float h1[32];
  #pragma unroll
  for (int o = 0; o < 32; o++) {
    float s = sB1[o];
    #pragma unroll
    for (int k = 0; k < 32; k++) s = fmaf(in[k], sW1[k * 32 + o], s);
    h1[o] = fmaxf(s, 0.f);
  }
  float h2[16];
  #pragma unroll
  for (int o = 0; o < 16; o++) {
    float s = sB2[o];
    #pragma unroll
    for (int k = 0; k < 32; k++) s = fmaf(h1[k], sW2[k * 16 + o], s);
    h2[o] = fmaxf(s, 0.f);
  }
  float o0[16];
  #pragma unroll
  for (int o = 0; o < 16; o++) {
    float s = sB3[o];
    #pragma unroll
    for (int k = 0; k < 16; k++) s = fmaf(h2[k], sW3[k * 16 + o], s);
    o0[o] = s;
  }
  float4* yp = reinterpret_cast<float4*>(y + (size_t)g * 16);
  #pragma unroll
  for (int q = 0; q < 4; q++)
    yp[q] = make_float4(o0[q * 4], o0[q * 4 + 1], o0[q * 4 + 2], o0[q * 4 + 3]);
}

// ---------------------------------------------------------------------------

extern "C" void kernel_launch(void* const* d_in, const int* in_sizes, int n_in,
                              void* d_out, int out_size, void* d_ws, size_t ws_size,
                              hipStream_t stream) {
  const float* x = (const float*)d_in[0];
  const int* ei = (const int*)d_in[1];
  const int* batch = (const int*)d_in[2];
  const float* m1w1 = (const float*)d_in[4];  const float* m1b1 = (const float*)d_in[5];
  const float* m1w2 = (const float*)d_in[6];  const float* m1b2 = (const float*)d_in[7];
  const float* m1w3 = (const float*)d_in[8];  const float* m1b3 = (const float*)d_in[9];
  const float* m2w1 = (const float*)d_in[10]; const float* m2b1 = (const float*)d_in[11];
  const float* m2w2 = (const float*)d_in[12]; const float* m2b2 = (const float*)d_in[13];
  const float* m2w3 = (const float*)d_in[14]; const float* m2b3 = (const float*)d_in[15];
  const float* mdw1 = (const float*)d_in[16]; const float* mdb1 = (const float*)d_in[17];
  const float* mdw2 = (const float*)d_in[18]; const float* mdb2 = (const float*)d_in[19];
  const float* mdw3 = (const float*)d_in[20]; const float* mdb3 = (const float*)d_in[21];
  const float* mgw1 = (const float*)d_in[22]; const float* mgb1 = (const float*)d_in[23];
  const float* mgw2 = (const float*)d_in[24]; const float* mgb2 = (const float*)d_in[25];
  const float* mgw3 = (const float*)d_in[26]; const float* mgb3 = (const float*)d_in[27];

  int N = in_sizes[0] / 16;
  int E = in_sizes[1] / 2;
  int G = (out_size - N * 16 - 16) / 16;
  const int* rowp = ei;       // aggregation (destination) index
  const int* colp = ei + E;   // message source index

  float* xn = (float*)d_out;
  float* yv = xn + (size_t)N * 16;
  float* zv = yv + (size_t)G * 16;

  int nb = (N + BSZ - 1) / BSZ;
  int NT = (E + TSZ - 1) / TSZ;
  int NBP = (nb + 63) & ~63;
  int CSZ = (NT + CH - 1) / CH;

  size_t off = 0;
  auto alloc = [&](size_t bytes) -> size_t {
    off = (off + 255) & ~(size_t)255;
    size_t o = off; off += bytes; return o;
  };
  char* ws = (char*)d_ws;
  size_t o_deg  = alloc((size_t)N * 4);
  size_t o_hs16 = alloc((size_t)N * 16);
  size_t o_cnt  = alloc((size_t)4 * NBMAX * 4);          // tot_r, offs_r, tot_c, offs_c
  size_t o_Hr   = alloc((size_t)NT * NBP * 4);
  size_t o_Hc   = alloc((size_t)NT * NBP * 4);
  size_t o_S    = alloc((size_t)2 * CH * NBP * 4);
  size_t o_eb   = alloc(((size_t)E + 4 * NBMAX) * 4);    // padded row buckets
  size_t o_eb2  = alloc((size_t)E * 2);
  size_t o_pool = alloc((size_t)G * 32 * 4);             // fallback only
  size_t need = off;

  bool bucketed = (ws_size >= need) && (nb <= NBMAX) && (N <= (1 << 18));

  if (bucketed) {
    unsigned* deg = (unsigned*)(ws + o_deg);
    uint4* hs16 = (uint4*)(ws + o_hs16);
    unsigned* tot_r  = (unsigned*)(ws + o_cnt);
    unsigned* offs_r = tot_r + NBMAX;
    unsigned* tot_c  = tot_r + 2 * NBMAX;
    unsigned* offs_c = tot_r + 3 * NBMAX;
    unsigned* Hr = (unsigned*)(ws + o_Hr);
    unsigned* Hc = (unsigned*)(ws + o_Hc);
    unsigned* Sr = (unsigned*)(ws + o_S);
    unsigned* Sc = Sr + CH * NBP;
    unsigned* ebuf = (unsigned*)(ws + o_eb);
    unsigned short* ebuf2 = (unsigned short*)(ws + o_eb2);

    int gcol = (CH * NBP + 255) / 256;
    k_hist<<<NT, 256, 0, stream>>>(rowp, colp, E, NBP, Hr, Hc);
    k_colsum2<<<2 * gcol, 256, 0, stream>>>(Hr, Sr, Hc, Sc, NT, NBP, CSZ, gcol);
    k_colapply2<<<2 * gcol, 256, 0, stream>>>(Hr, Sr, tot_r, Hc, Sc, tot_c,
                                              NT, NBP, nb, CSZ, gcol);
    k_scan2<<<2, 1024, 0, stream>>>(tot_r, offs_r, tot_c, offs_c, nb);
    k_scat2<<<NT, 512, 0, stream>>>(rowp, colp, E, nb, NBP, Hr, Hc,
                                    offs_r, offs_c, ebuf, ebuf2);
    k_degm<<<nb, 256, 0, stream>>>(ebuf2, offs_c, tot_c, x,
                                   m1w1, m1b1, m1w2, m1b2, m1w3, m1b3,
                                   deg, hs16, N);
    k_agg<<<nb, 512, 0, stream>>>(ebuf, offs_r, tot_r, hs16, deg,
                                  m2w1, m2b1, m2w2, m2b2, m2w3, m2b3, xn, N);
    k_poold<<<G, 256, 0, stream>>>(x, xn, batch,
                                   mdw1, mdb1, mdw2, mdb2, mdw3, mdb3, yv, N);
    k_z<<<1, 256, 0, stream>>>(yv, mgw1, mgb1, mgw2, mgb2, mgw3, mgb3, zv, G);
  } else {
    unsigned* deg = (unsigned*)ws;
    float* acc = (float*)(ws + (size_t)N * 4);
    float* hs  = (float*)(ws + (size_t)N * 36);
    float* pool = (float*)(ws + (size_t)N * 68);

    hipMemsetAsync(ws, 0, (size_t)N * 36, stream);
    const int TB = 256;
    k_deg_atomic<<<(E + TB - 1) / TB, TB, 0, stream>>>(colp, deg, E);
    k_mlp1f<<<(N + TB - 1) / TB, TB, 0, stream>>>(x, deg, m1w1, m1b1, m1w2, m1b2, m1w3, m1b3, hs, N);
    k_scatter_atomic<<<(E + TB - 1) / TB, TB, 0, stream>>>(rowp, colp, hs, acc, E);
    k_finalize<<<(N + TB - 1) / TB, TB, 0, stream>>>(hs, acc, deg, m2w1, m2b1, m2w2, m2b2, m2w3, m2b3, xn, N);
    k_pool<<<G, TB, 0, stream>>>(x, xn, batch, pool, N);
    k_dag<<<(G + TB - 1) / TB, TB, 0, stream>>>(pool, mdw1, mdb1, mdw2, mdb2, mdw3, mdb3, yv, G);
    k_z<<<1, TB, 0, stream>>>(yv, mgw1, mgb1, mgw2, mgb2, mgw3, mgb3, zv, G);
  }
}